// Round 1
// baseline (168.958 us; speedup 1.0000x reference)
//
#include <hip/hip_runtime.h>
#include <math.h>

#define NB 8
#define NQ 100
#define NCP1 3
#define NC 2
#define HIN 128
#define WIN 128
#define HOUT 512
#define WOUT 512

#if __has_builtin(__builtin_amdgcn_exp2f)
#define EXP2F(x) __builtin_amdgcn_exp2f(x)
#else
#define EXP2F(x) exp2f(x)
#endif
#if __has_builtin(__builtin_amdgcn_rcpf)
#define RCPF(x) __builtin_amdgcn_rcpf(x)
#else
#define RCPF(x) (1.0f / (x))
#endif

// One block = (b, k) where k indexes 4 consecutive output rows y=4k..4k+3.
// Per q: stage 3 raw mask rows (k-1,k,k+1 clamped) global->LDS (double-buffered,
// prefetch q+1), h-interp once into H[3][512] (weights pre-scaled by -log2e),
// then 256 threads each do 8 pixels: vlerp + sigmoid + 2 class-FMAs.
__global__ __launch_bounds__(256, 4)
void m2f_fused(const float* __restrict__ cls,
               const float* __restrict__ masks,
               float* __restrict__ out) {
  const int k   = blockIdx.x;   // 0..127
  const int b   = blockIdx.y;   // 0..7
  const int tid = threadIdx.x;  // 0..255

  __shared__ float  raw[2][3][WIN];   // double-buffered raw rows
  __shared__ float  Hrow[3][WOUT];    // h-interpolated rows (scaled by -log2e)
  __shared__ float2 pq[NQ];           // class probs (c0,c1) per q

  // ---- inline class softmax (keep first NC of NCP1) ----
  if (tid < NQ) {
    const float* cl = cls + (b * NQ + tid) * NCP1;
    float a0 = cl[0], a1 = cl[1], a2 = cl[2];
    float mx = fmaxf(a0, fmaxf(a1, a2));
    const float L2E = 1.4426950408889634f;
    float e0 = EXP2F((a0 - mx) * L2E);
    float e1 = EXP2F((a1 - mx) * L2E);
    float e2 = EXP2F((a2 - mx) * L2E);
    float inv = RCPF(e0 + e1 + e2);
    pq[tid] = make_float2(e0 * inv, e1 * inv);
  }

  // clamped source rows for this k
  const int r0 = (k > 0) ? k - 1 : 0;
  const int r1 = k;
  const int r2 = (k < HIN - 1) ? k + 1 : HIN - 1;

  // ---- loader: threads 0..95 fetch 3 rows x 128 floats as float4 ----
  const bool loader = tid < 96;
  const int  lrow = tid >> 5;          // 0..2
  const int  lc   = (tid & 31) * 4;    // col
  const int  lri  = (lrow == 0) ? r0 : (lrow == 1 ? r1 : r2);
  const float* mbase = masks + (size_t)b * NQ * HIN * WIN + (size_t)lri * WIN + lc;

  // ---- producer constants (h-interp), hoisted out of q loop ----
  // thread t produces x = 2t, 2t+1.  x=4m+s: t even -> s=0,1 cols (m-1,m);
  // t odd -> s=2,3 cols (m,m+1).  Weights folded with -log2(e).
  const int  pm   = tid >> 1;
  const bool podd = tid & 1;
  const int  cL = podd ? pm : (pm > 0 ? pm - 1 : 0);
  const int  cR = podd ? (pm < WIN - 1 ? pm + 1 : WIN - 1) : pm;
  const float NL2E = -1.4426950408889634f;
  const float wl0 = (podd ? 0.875f : 0.375f) * NL2E;
  const float wr0 = (podd ? 0.125f : 0.625f) * NL2E;
  const float wl1 = (podd ? 0.625f : 0.125f) * NL2E;
  const float wr1 = (podd ? 0.375f : 0.875f) * NL2E;
  const int  px0 = tid * 2;

  // ---- consumer constants: row phase cr = tid>>6, 8 px per thread ----
  const int cr   = tid >> 6;      // output row phase 0..3 (y = 4k+cr)
  const int lane = tid & 63;
  const int x0   = lane * 8;
  const int rlo  = cr >> 1;       // H-row pair: (0,1) for cr<2, (1,2) else
  const float wy0 = (cr == 0) ? 0.375f : (cr == 1) ? 0.125f
                  : (cr == 2) ? 0.875f : 0.625f;
  const float wy1 = 1.0f - wy0;   // exact for these dyadic weights

  float accA[8], accB[8];
#pragma unroll
  for (int j = 0; j < 8; ++j) { accA[j] = 0.f; accB[j] = 0.f; }

  float4 ld;
  if (loader) {
    ld = *(const float4*)mbase;
    *(float4*)&raw[0][lrow][lc] = ld;
  }
  __syncthreads();

  for (int q = 0; q < NQ; ++q) {
    const int buf = q & 1;
    // prefetch next q's rows into registers (latency covered by compute below)
    if (q + 1 < NQ && loader)
      ld = *(const float4*)(mbase + (size_t)(q + 1) * HIN * WIN);

    // producer: raw[buf] -> Hrow (pre-scaled by -log2e)
#pragma unroll
    for (int rho = 0; rho < 3; ++rho) {
      float a = raw[buf][rho][cL];
      float c = raw[buf][rho][cR];
      float h0 = wl0 * a + wr0 * c;
      float h1 = wl1 * a + wr1 * c;
      *(float2*)&Hrow[rho][px0] = make_float2(h0, h1);
    }
    __syncthreads();

    // consumer: 8 pixels, vectorized LDS reads
    const float2 pp = pq[q];
    float hlo[8], hhi[8];
    *(float4*)&hlo[0] = *(const float4*)&Hrow[rlo][x0];
    *(float4*)&hlo[4] = *(const float4*)&Hrow[rlo][x0 + 4];
    *(float4*)&hhi[0] = *(const float4*)&Hrow[rlo + 1][x0];
    *(float4*)&hhi[4] = *(const float4*)&Hrow[rlo + 1][x0 + 4];
#pragma unroll
    for (int j = 0; j < 8; ++j) {
      float v  = wy0 * hlo[j] + wy1 * hhi[j];  // = -log2e * upsampled logit
      float t  = EXP2F(v);                     // = exp(-x)
      float sg = RCPF(1.0f + t);               // sigmoid
      accA[j] = fmaf(pp.x, sg, accA[j]);
      accB[j] = fmaf(pp.y, sg, accB[j]);
    }

    // stage prefetched rows into the other raw buffer
    if (q + 1 < NQ && loader)
      *(float4*)&raw[buf ^ 1][lrow][lc] = ld;
    __syncthreads();
  }

  // ---- store: y = 4k+cr, 8 consecutive x per thread, both classes ----
  const int y = 4 * k + cr;
  float* o0 = out + ((size_t)(b * NC + 0) * HOUT + y) * WOUT + x0;
  float* o1 = out + ((size_t)(b * NC + 1) * HOUT + y) * WOUT + x0;
  *(float4*)o0       = make_float4(accA[0], accA[1], accA[2], accA[3]);
  *(float4*)(o0 + 4) = make_float4(accA[4], accA[5], accA[6], accA[7]);
  *(float4*)o1       = make_float4(accB[0], accB[1], accB[2], accB[3]);
  *(float4*)(o1 + 4) = make_float4(accB[4], accB[5], accB[6], accB[7]);
}

extern "C" void kernel_launch(void* const* d_in, const int* in_sizes, int n_in,
                              void* d_out, int out_size, void* d_ws, size_t ws_size,
                              hipStream_t stream) {
  const float* cls   = (const float*)d_in[0];   // [8,100,3] fp32
  const float* masks = (const float*)d_in[1];   // [8,100,128,128] fp32
  float* out = (float*)d_out;                   // [8,2,512,512] fp32
  dim3 grid(HIN, NB);   // 128 k-groups x 8 batches = 1024 blocks
  m2f_fused<<<grid, 256, 0, stream>>>(cls, masks, out);
}

// Round 2
// 156.465 us; speedup vs baseline: 1.0798x; 1.0798x over previous
//
#include <hip/hip_runtime.h>
#include <math.h>

#define NB 8
#define NQ 100
#define NCP1 3
#define NC 2
#define HIN 128
#define WIN 128
#define HOUT 512
#define WOUT 512

#if __has_builtin(__builtin_amdgcn_exp2f)
#define EXP2F(x) __builtin_amdgcn_exp2f(x)
#else
#define EXP2F(x) exp2f(x)
#endif
#if __has_builtin(__builtin_amdgcn_rcpf)
#define RCPF(x) __builtin_amdgcn_rcpf(x)
#else
#define RCPF(x) (1.0f / (x))
#endif

// Block = (b, k): 4 output rows y = 4k..4k+3.  Thread (h = tid>>7, l = tid&127)
// owns output rows y = 4k+2h, 4k+2h+1 at cols 4l..4l+3.  Its 8 pixels need only
// 6 input floats per q: cols {l-1,l,l+1} (clamped) x rows {ra,rb} (clamped).
// Loaded straight from global with per-thread-constant offsets (clamping baked
// into addresses at setup). No staging LDS, no per-q barriers, no bank
// conflicts; L1/L2 serve the 6-way intra-wave overlap. Depth-2 software
// pipeline (12 loads in flight) hides L2/HBM latency.
__global__ __launch_bounds__(256, 4)
void m2f_fused(const float* __restrict__ cls,
               const float* __restrict__ masks,
               float* __restrict__ out) {
  const int k   = blockIdx.x;   // 0..127
  const int b   = blockIdx.y;   // 0..7
  const int tid = threadIdx.x;  // 0..255

  __shared__ float2 pq[NQ];     // class probs (c0,c1) per q

  // ---- inline class softmax (keep first NC of NCP1) ----
  if (tid < NQ) {
    const float* cl = cls + (b * NQ + tid) * NCP1;
    float a0 = cl[0], a1 = cl[1], a2 = cl[2];
    float mx = fmaxf(a0, fmaxf(a1, a2));
    const float L2E = 1.4426950408889634f;
    float e0 = EXP2F((a0 - mx) * L2E);
    float e1 = EXP2F((a1 - mx) * L2E);
    float e2 = EXP2F((a2 - mx) * L2E);
    float inv = RCPF(e0 + e1 + e2);
    pq[tid] = make_float2(e0 * inv, e1 * inv);
  }
  __syncthreads();   // the only barrier in the kernel

  const int h = tid >> 7;       // output-row pair: 0 -> rows 4k,4k+1 ; 1 -> 4k+2,4k+3
  const int l = tid & 127;      // col group: x = 4l..4l+3

  // clamped input rows for this half
  const int ra = h ? k : (k > 0 ? k - 1 : 0);
  const int rb = h ? (k < HIN - 1 ? k + 1 : HIN - 1) : k;
  // clamped input cols
  const int lm = (l > 0) ? l - 1 : 0;
  const int lp = (l < WIN - 1) ? l + 1 : WIN - 1;

  // vertical weights (half-pixel, scale 4), folded with -log2(e) so that
  // sigmoid(x) = rcp(1 + exp2(v)) with v = -log2e * x
  const float NL2E = -1.4426950408889634f;
  const float wA0 = (h ? 0.875f : 0.375f) * NL2E;  // row y0
  const float wB0 = (h ? 0.125f : 0.625f) * NL2E;
  const float wA1 = (h ? 0.625f : 0.125f) * NL2E;  // row y1
  const float wB1 = (h ? 0.375f : 0.875f) * NL2E;

  const float* base = masks + (size_t)b * NQ * HIN * WIN;
  const int oAm = ra * WIN + lm, oA0 = ra * WIN + l, oAp = ra * WIN + lp;
  const int oBm = rb * WIN + lm, oB0 = rb * WIN + l, oBp = rb * WIN + lp;

  float c0r0[4], c0r1[4], c1r0[4], c1r1[4];
#pragma unroll
  for (int j = 0; j < 4; ++j) { c0r0[j] = 0.f; c0r1[j] = 0.f; c1r0[j] = 0.f; c1r1[j] = 0.f; }

  float P0[6], P1[6];

#define LOADSET(P, qq)                                                \
  do {                                                                \
    const float* m_ = base + (size_t)(qq) * (HIN * WIN);              \
    (P)[0] = m_[oAm]; (P)[1] = m_[oA0]; (P)[2] = m_[oAp];             \
    (P)[3] = m_[oBm]; (P)[4] = m_[oB0]; (P)[5] = m_[oBp];             \
  } while (0)

#define COMPUTE(P, pp)                                                \
  do {                                                                \
    float t0m = fmaf(wA0, (P)[0], wB0 * (P)[3]);                      \
    float t00 = fmaf(wA0, (P)[1], wB0 * (P)[4]);                      \
    float t0p = fmaf(wA0, (P)[2], wB0 * (P)[5]);                      \
    float t1m = fmaf(wA1, (P)[0], wB1 * (P)[3]);                      \
    float t10 = fmaf(wA1, (P)[1], wB1 * (P)[4]);                      \
    float t1p = fmaf(wA1, (P)[2], wB1 * (P)[5]);                      \
    float v0[4], v1[4];                                               \
    v0[0] = fmaf(0.375f, t0m, 0.625f * t00);                          \
    v0[1] = fmaf(0.125f, t0m, 0.875f * t00);                          \
    v0[2] = fmaf(0.875f, t00, 0.125f * t0p);                          \
    v0[3] = fmaf(0.625f, t00, 0.375f * t0p);                          \
    v1[0] = fmaf(0.375f, t1m, 0.625f * t10);                          \
    v1[1] = fmaf(0.125f, t1m, 0.875f * t10);                          \
    v1[2] = fmaf(0.875f, t10, 0.125f * t1p);                          \
    v1[3] = fmaf(0.625f, t10, 0.375f * t1p);                          \
    _Pragma("unroll")                                                 \
    for (int j = 0; j < 4; ++j) {                                     \
      float s0 = RCPF(1.0f + EXP2F(v0[j]));                           \
      float s1 = RCPF(1.0f + EXP2F(v1[j]));                           \
      c0r0[j] = fmaf((pp).x, s0, c0r0[j]);                            \
      c1r0[j] = fmaf((pp).y, s0, c1r0[j]);                            \
      c0r1[j] = fmaf((pp).x, s1, c0r1[j]);                            \
      c1r1[j] = fmaf((pp).y, s1, c1r1[j]);                            \
    }                                                                 \
  } while (0)

  LOADSET(P0, 0);
  LOADSET(P1, 1);

  for (int q = 0; q < NQ; q += 2) {
    const float2 pp0 = pq[q];
    const float2 pp1 = pq[q + 1];
    COMPUTE(P0, pp0);
    if (q + 2 < NQ) LOADSET(P0, q + 2);
    COMPUTE(P1, pp1);
    if (q + 3 < NQ) LOADSET(P1, q + 3);
  }

  // ---- stores: rows y0,y0+1, cols 4l..4l+3, both classes ----
  const int y0 = 4 * k + 2 * h;
  const int x0 = 4 * l;
  float* o0 = out + (((size_t)b * NC + 0) * HOUT + y0) * WOUT + x0;
  float* o1 = out + (((size_t)b * NC + 1) * HOUT + y0) * WOUT + x0;
  *(float4*)o0          = make_float4(c0r0[0], c0r0[1], c0r0[2], c0r0[3]);
  *(float4*)(o0 + WOUT) = make_float4(c0r1[0], c0r1[1], c0r1[2], c0r1[3]);
  *(float4*)o1          = make_float4(c1r0[0], c1r0[1], c1r0[2], c1r0[3]);
  *(float4*)(o1 + WOUT) = make_float4(c1r1[0], c1r1[1], c1r1[2], c1r1[3]);
}

extern "C" void kernel_launch(void* const* d_in, const int* in_sizes, int n_in,
                              void* d_out, int out_size, void* d_ws, size_t ws_size,
                              hipStream_t stream) {
  const float* cls   = (const float*)d_in[0];   // [8,100,3] fp32
  const float* masks = (const float*)d_in[1];   // [8,100,128,128] fp32
  float* out = (float*)d_out;                   // [8,2,512,512] fp32
  dim3 grid(HIN, NB);   // 128 k-groups x 8 batches = 1024 blocks
  m2f_fused<<<grid, 256, 0, stream>>>(cls, masks, out);
}